// Round 15
// baseline (158.048 us; speedup 1.0000x reference)
//
#include <hip/hip_runtime.h>
#include <math.h>

#define N_NODES 50000
#define N_EDGES 800000
#define HIDDEN  64
#define NPART   500                   // partition blocks
#define PCHUNK  1600                  // edges per partition block
#define NBUCK   32
#define SLICE   1568                  // 32*1568 = 50176 >= 50000
#define CAPB    128                   // pow2 cap: mean 50 + 11 sigma
#define NSUB    10                    // agg sub-blocks per bucket
#define BPS     (NPART / NSUB)        // 50
#define SPAN    (BPS * CAPB)          // 6400 words per (bucket,sub)
#define FSPAN   (NPART * CAPB)        // 64000 words per bucket

// ws: cnts u32[NPART*32] 64KB | bks u32[32*NPART*CAPB] 8.2MB |
//     part1 f32[32*NSUB*SLICE] 2MB | part2 f32x2[...] 4MB | dinv[N] | g[N] | z f2[N]

// ---- K1: single-pass write-combined radix partition (no global atomics) ----
__global__ __launch_bounds__(256)
void k_part(const int* __restrict__ row, const int* __restrict__ col,
            unsigned* __restrict__ cnts, unsigned* __restrict__ bks) {
    __shared__ unsigned stage[NBUCK * CAPB];        // 16 KB
    __shared__ unsigned cnt2[NBUCK];
    const int t   = threadIdx.x;
    const int blk = blockIdx.x;
    const int e0  = blk * PCHUNK;
    if (t < NBUCK) cnt2[t] = 0u;
    __syncthreads();
    const int4* c4 = (const int4*)(col + e0);
    const int4* r4 = (const int4*)(row + e0);
    for (int i = t; i < PCHUNK / 4; i += 256) {     // 400 int4s
        int4 cv = c4[i];
        int4 rv = r4[i];
#pragma unroll
        for (int k = 0; k < 4; ++k) {
            int c = (&cv.x)[k], r = (&rv.x)[k];
            int b = c / SLICE;                      // magic-mul div
            unsigned off = atomicAdd(&cnt2[b], 1u);
            if (off < CAPB)
                stage[(b << 7) + off] = ((unsigned)(c - b * SLICE) << 16) | (unsigned)r;
        }
    }
    __syncthreads();
    if (t < NBUCK) cnts[blk * NBUCK + t] = min(cnt2[t], (unsigned)CAPB);
    // coalesced flush: 128-word contiguous runs per bucket
    for (int i = t; i < NBUCK * CAPB; i += 256) {
        int b = i >> 7, o = i & 127;
        bks[((size_t)b * NPART + blk) * CAPB + o] = stage[i];
    }
}

// ---- K2: fused degree count + dinv + g (one block per bucket, predicated) ----
__global__ __launch_bounds__(512)
void k_degg(const unsigned* __restrict__ cnts, const unsigned* __restrict__ bks,
            const float* __restrict__ x, float* __restrict__ dinv,
            float* __restrict__ g) {
    __shared__ unsigned acc[SLICE];                 // 6.3 KB
    __shared__ unsigned short scnt[NPART];          // 1 KB
    const int b = blockIdx.x, t = threadIdx.x;
    for (int i = t; i < SLICE; i += 512) acc[i] = 0u;
    for (int i = t; i < NPART; i += 512) scnt[i] = (unsigned short)cnts[i * NBUCK + b];
    __syncthreads();
    const unsigned* src = bks + (size_t)b * NPART * CAPB;   // contiguous 256 KB
    for (int i = t; i < FSPAN; i += 512) {
        unsigned v = src[i];                        // coalesced
        if ((unsigned)(i & 127) < scnt[i >> 7]) atomicAdd(&acc[v >> 16], 1u);
    }
    __syncthreads();
    const int n0 = b * SLICE;
    for (int i = t; i < SLICE; i += 512) {
        int n = n0 + i;
        if (n < N_NODES) {
            float di = rsqrtf((float)(acc[i] + 1)); // +1 self-loop
            dinv[n] = di;
            g[n] = di * x[n];
        }
    }
}

// ---- K3: layer-1 aggregation (predicated, shift/mask indexing) ----
__global__ __launch_bounds__(256)
void k_agg1(const unsigned* __restrict__ cnts, const unsigned* __restrict__ bks,
            const float* __restrict__ g, float* __restrict__ part1) {
    __shared__ float acc[SLICE];
    __shared__ unsigned short scnt[BPS];
    const int b = blockIdx.x / NSUB;
    const int s = blockIdx.x % NSUB;
    for (int i = threadIdx.x; i < SLICE; i += 256) acc[i] = 0.0f;
    if (threadIdx.x < BPS)
        scnt[threadIdx.x] = (unsigned short)cnts[(s * BPS + threadIdx.x) * NBUCK + b];
    __syncthreads();
    const unsigned* src = bks + ((size_t)b * NPART + s * BPS) * CAPB;
    for (int i = threadIdx.x; i < SPAN; i += 256) {
        unsigned v = src[i];                        // coalesced
        if ((unsigned)(i & 127) < scnt[i >> 7])
            atomicAdd(&acc[v >> 16], g[v & 0xFFFFu]);   // LDS atomic + L2 gather
    }
    __syncthreads();
    float* dst = part1 + (size_t)blockIdx.x * SLICE;
    for (int i = threadIdx.x; i < SLICE; i += 256) dst[i] = acc[i];
}

// ---- K4: reduce NSUB partials + fused MLP -> z ----
__global__ __launch_bounds__(256)
void k_mlp(const float* __restrict__ part1, const float* __restrict__ g,
           const float* __restrict__ dinv,
           const float* __restrict__ W1, const float* __restrict__ b1,
           const float* __restrict__ W2, float2* __restrict__ z) {
    int n = blockIdx.x * 256 + threadIdx.x;
    if (n >= N_NODES) return;
    int b = n / SLICE, cl = n - b * SLICE;
    const float* p = part1 + (size_t)b * NSUB * SLICE + cl;
    float t = 0.0f;
#pragma unroll
    for (int s = 0; s < NSUB; ++s) t += p[(size_t)s * SLICE];
    float di = dinv[n];
    float sv = di * (t + g[n]);
    float y0 = 0.0f, y1 = 0.0f;
#pragma unroll
    for (int k = 0; k < HIDDEN; ++k) {              // wave-uniform -> s_load
        float h = fmaxf(sv * W1[k] + b1[k], 0.0f);
        y0 += h * W2[2 * k];
        y1 += h * W2[2 * k + 1];
    }
    z[n] = make_float2(di * y0, di * y1);
}

// ---- K5: layer-2 aggregation (float2, predicated) ----
__global__ __launch_bounds__(256)
void k_agg2(const unsigned* __restrict__ cnts, const unsigned* __restrict__ bks,
            const float2* __restrict__ z, float2* __restrict__ part2) {
    __shared__ float ax[SLICE];
    __shared__ float ay[SLICE];
    __shared__ unsigned short scnt[BPS];
    const int b = blockIdx.x / NSUB;
    const int s = blockIdx.x % NSUB;
    for (int i = threadIdx.x; i < SLICE; i += 256) { ax[i] = 0.0f; ay[i] = 0.0f; }
    if (threadIdx.x < BPS)
        scnt[threadIdx.x] = (unsigned short)cnts[(s * BPS + threadIdx.x) * NBUCK + b];
    __syncthreads();
    const unsigned* src = bks + ((size_t)b * NPART + s * BPS) * CAPB;
    for (int i = threadIdx.x; i < SPAN; i += 256) {
        unsigned v = src[i];
        if ((unsigned)(i & 127) < scnt[i >> 7]) {
            float2 zz = z[v & 0xFFFFu];
            unsigned cl = v >> 16;
            atomicAdd(&ax[cl], zz.x);
            atomicAdd(&ay[cl], zz.y);
        }
    }
    __syncthreads();
    float2* dst = part2 + (size_t)blockIdx.x * SLICE;
    for (int i = threadIdx.x; i < SLICE; i += 256) dst[i] = make_float2(ax[i], ay[i]);
}

// ---- K6: reduce NSUB float2 partials + epilogue -> out ----
__global__ __launch_bounds__(256)
void k_final(const float2* __restrict__ part2, const float2* __restrict__ z,
             const float* __restrict__ dinv, const float* __restrict__ b2,
             float2* __restrict__ out) {
    int n = blockIdx.x * 256 + threadIdx.x;
    if (n >= N_NODES) return;
    int b = n / SLICE, cl = n - b * SLICE;
    const float2* p = part2 + (size_t)b * NSUB * SLICE + cl;
    float Tx = 0.0f, Ty = 0.0f;
#pragma unroll
    for (int s = 0; s < NSUB; ++s) {
        float2 v = p[(size_t)s * SLICE];
        Tx += v.x; Ty += v.y;
    }
    float di = dinv[n];
    float2 zn = z[n];
    out[n] = make_float2(di * (Tx + zn.x) + b2[0], di * (Ty + zn.y) + b2[1]);
}

// ================= launch =================

extern "C" void kernel_launch(void* const* d_in, const int* in_sizes, int n_in,
                              void* d_out, int out_size, void* d_ws, size_t ws_size,
                              hipStream_t stream) {
    const float* x  = (const float*)d_in[0];
    const int*   ei = (const int*)d_in[1];
    const float* W1 = (const float*)d_in[2];
    const float* b1 = (const float*)d_in[3];
    const float* W2 = (const float*)d_in[4];
    const float* b2 = (const float*)d_in[5];

    const int* row = ei;
    const int* col = ei + N_EDGES;

    char* p = (char*)d_ws;
    unsigned* cnts  = (unsigned*)p;  p += (size_t)NPART * NBUCK * 4;           // 64 KB
    unsigned* bks   = (unsigned*)p;  p += (size_t)NBUCK * NPART * CAPB * 4;    // 8.2 MB
    float*    part1 = (float*)p;     p += (size_t)NBUCK * NSUB * SLICE * 4;    // 2.0 MB
    float2*   part2 = (float2*)p;    p += (size_t)NBUCK * NSUB * SLICE * 8;    // 4.0 MB
    float*    dinv  = (float*)p;     p += N_NODES * 4;
    float*    g     = (float*)p;     p += N_NODES * 4;
    float2*   z     = (float2*)p;

    const int gA = NBUCK * NSUB;            // 320 agg blocks
    const int gN = (N_NODES + 255) / 256;   // 196

    k_part <<<NPART, 256, 0, stream>>>(row, col, cnts, bks);
    k_degg <<<NBUCK, 512, 0, stream>>>(cnts, bks, x, dinv, g);
    k_agg1 <<<gA,    256, 0, stream>>>(cnts, bks, g, part1);
    k_mlp  <<<gN,    256, 0, stream>>>(part1, g, dinv, W1, b1, W2, z);
    k_agg2 <<<gA,    256, 0, stream>>>(cnts, bks, z, part2);
    k_final<<<gN,    256, 0, stream>>>(part2, z, dinv, b2, (float2*)d_out);
}

// Round 16
// 123.215 us; speedup vs baseline: 1.2827x; 1.2827x over previous
//
#include <hip/hip_runtime.h>
#include <math.h>

#define N_NODES 50000
#define N_EDGES 800000
#define HIDDEN  64
#define NPART   500                   // partition blocks
#define PCHUNK  1600                  // edges per partition block
#define NBUCK   32
#define SLICE   1568                  // 32*1568 = 50176 >= 50000
#define CAPB    128                   // pow2 cap: mean 50 + 11 sigma
#define NSUB    10                    // agg sub-blocks per bucket
#define BPS     (NPART / NSUB)        // 50
#define SPAN    (BPS * CAPB)          // 6400 words per (bucket,sub)

// ws: cnts u32[NPART*32] 64KB | bks u32[32*NPART*CAPB] 8.2MB |
//     part_deg u32[32*NSUB*SLICE] 2MB | part1 f32[...] 2MB | part2 f32x2[...] 4MB |
//     dinv[N] | g[N] | z f2[N]

// ---- K1: single-pass write-combined radix partition (no global atomics) ----
__global__ __launch_bounds__(256)
void k_part(const int* __restrict__ row, const int* __restrict__ col,
            unsigned* __restrict__ cnts, unsigned* __restrict__ bks) {
    __shared__ unsigned stage[NBUCK * CAPB];        // 16 KB
    __shared__ unsigned cnt2[NBUCK];
    const int t   = threadIdx.x;
    const int blk = blockIdx.x;
    const int e0  = blk * PCHUNK;
    if (t < NBUCK) cnt2[t] = 0u;
    __syncthreads();
    const int4* c4 = (const int4*)(col + e0);
    const int4* r4 = (const int4*)(row + e0);
    for (int i = t; i < PCHUNK / 4; i += 256) {     // 400 int4s
        int4 cv = c4[i];
        int4 rv = r4[i];
#pragma unroll
        for (int k = 0; k < 4; ++k) {
            int c = (&cv.x)[k], r = (&rv.x)[k];
            int b = c / SLICE;                      // magic-mul div
            unsigned off = atomicAdd(&cnt2[b], 1u);
            if (off < CAPB)
                stage[(b << 7) + off] = ((unsigned)(c - b * SLICE) << 16) | (unsigned)r;
        }
    }
    __syncthreads();
    if (t < NBUCK) cnts[blk * NBUCK + t] = min(cnt2[t], (unsigned)CAPB);
    // coalesced flush: 128-word contiguous runs per bucket
    for (int i = t; i < NBUCK * CAPB; i += 256) {
        int b = i >> 7, o = i & 127;
        bks[((size_t)b * NPART + blk) * CAPB + o] = stage[i];
    }
}

// ---- K2: per-slice degree partials (320 blocks, predicated, shift/mask) ----
__global__ __launch_bounds__(256)
void k_deg(const unsigned* __restrict__ cnts, const unsigned* __restrict__ bks,
           unsigned* __restrict__ part_deg) {
    __shared__ unsigned acc[SLICE];                 // 6.3 KB
    __shared__ unsigned short scnt[BPS];
    const int b = blockIdx.x / NSUB;
    const int s = blockIdx.x % NSUB;
    for (int i = threadIdx.x; i < SLICE; i += 256) acc[i] = 0u;
    if (threadIdx.x < BPS)
        scnt[threadIdx.x] = (unsigned short)cnts[(s * BPS + threadIdx.x) * NBUCK + b];
    __syncthreads();
    const unsigned* src = bks + ((size_t)b * NPART + s * BPS) * CAPB;
    for (int i = threadIdx.x; i < SPAN; i += 256) {
        unsigned v = src[i];                        // coalesced
        if ((unsigned)(i & 127) < scnt[i >> 7]) atomicAdd(&acc[v >> 16], 1u);
    }
    __syncthreads();
    unsigned* dst = part_deg + (size_t)blockIdx.x * SLICE;
    for (int i = threadIdx.x; i < SLICE; i += 256) dst[i] = acc[i];
}

// ---- K3: reduce NSUB degree partials -> dinv, g = rsqrt(deg+1)*x ----
__global__ __launch_bounds__(256)
void k_g(const unsigned* __restrict__ part_deg, const float* __restrict__ x,
         float* __restrict__ dinv, float* __restrict__ g) {
    int n = blockIdx.x * 256 + threadIdx.x;
    if (n >= N_NODES) return;
    int b = n / SLICE, cl = n - b * SLICE;
    const unsigned* p = part_deg + (size_t)b * NSUB * SLICE + cl;
    unsigned deg = 0;
#pragma unroll
    for (int s = 0; s < NSUB; ++s) deg += p[(size_t)s * SLICE];
    float di = rsqrtf((float)(deg + 1));            // +1 self-loop
    dinv[n] = di;
    g[n] = di * x[n];
}

// ---- K4: layer-1 aggregation (predicated, shift/mask) ----
__global__ __launch_bounds__(256)
void k_agg1(const unsigned* __restrict__ cnts, const unsigned* __restrict__ bks,
            const float* __restrict__ g, float* __restrict__ part1) {
    __shared__ float acc[SLICE];
    __shared__ unsigned short scnt[BPS];
    const int b = blockIdx.x / NSUB;
    const int s = blockIdx.x % NSUB;
    for (int i = threadIdx.x; i < SLICE; i += 256) acc[i] = 0.0f;
    if (threadIdx.x < BPS)
        scnt[threadIdx.x] = (unsigned short)cnts[(s * BPS + threadIdx.x) * NBUCK + b];
    __syncthreads();
    const unsigned* src = bks + ((size_t)b * NPART + s * BPS) * CAPB;
    for (int i = threadIdx.x; i < SPAN; i += 256) {
        unsigned v = src[i];                        // coalesced
        if ((unsigned)(i & 127) < scnt[i >> 7])
            atomicAdd(&acc[v >> 16], g[v & 0xFFFFu]);   // LDS atomic + L2 gather
    }
    __syncthreads();
    float* dst = part1 + (size_t)blockIdx.x * SLICE;
    for (int i = threadIdx.x; i < SLICE; i += 256) dst[i] = acc[i];
}

// ---- K5: reduce NSUB partials + fused MLP -> z ----
__global__ __launch_bounds__(256)
void k_mlp(const float* __restrict__ part1, const float* __restrict__ g,
           const float* __restrict__ dinv,
           const float* __restrict__ W1, const float* __restrict__ b1,
           const float* __restrict__ W2, float2* __restrict__ z) {
    int n = blockIdx.x * 256 + threadIdx.x;
    if (n >= N_NODES) return;
    int b = n / SLICE, cl = n - b * SLICE;
    const float* p = part1 + (size_t)b * NSUB * SLICE + cl;
    float t = 0.0f;
#pragma unroll
    for (int s = 0; s < NSUB; ++s) t += p[(size_t)s * SLICE];
    float di = dinv[n];
    float sv = di * (t + g[n]);
    float y0 = 0.0f, y1 = 0.0f;
#pragma unroll
    for (int k = 0; k < HIDDEN; ++k) {              // wave-uniform -> s_load
        float h = fmaxf(sv * W1[k] + b1[k], 0.0f);
        y0 += h * W2[2 * k];
        y1 += h * W2[2 * k + 1];
    }
    z[n] = make_float2(di * y0, di * y1);
}

// ---- K6: layer-2 aggregation (float2, predicated) ----
__global__ __launch_bounds__(256)
void k_agg2(const unsigned* __restrict__ cnts, const unsigned* __restrict__ bks,
            const float2* __restrict__ z, float2* __restrict__ part2) {
    __shared__ float ax[SLICE];
    __shared__ float ay[SLICE];
    __shared__ unsigned short scnt[BPS];
    const int b = blockIdx.x / NSUB;
    const int s = blockIdx.x % NSUB;
    for (int i = threadIdx.x; i < SLICE; i += 256) { ax[i] = 0.0f; ay[i] = 0.0f; }
    if (threadIdx.x < BPS)
        scnt[threadIdx.x] = (unsigned short)cnts[(s * BPS + threadIdx.x) * NBUCK + b];
    __syncthreads();
    const unsigned* src = bks + ((size_t)b * NPART + s * BPS) * CAPB;
    for (int i = threadIdx.x; i < SPAN; i += 256) {
        unsigned v = src[i];
        if ((unsigned)(i & 127) < scnt[i >> 7]) {
            float2 zz = z[v & 0xFFFFu];
            unsigned cl = v >> 16;
            atomicAdd(&ax[cl], zz.x);
            atomicAdd(&ay[cl], zz.y);
        }
    }
    __syncthreads();
    float2* dst = part2 + (size_t)blockIdx.x * SLICE;
    for (int i = threadIdx.x; i < SLICE; i += 256) dst[i] = make_float2(ax[i], ay[i]);
}

// ---- K7: reduce NSUB float2 partials + epilogue -> out ----
__global__ __launch_bounds__(256)
void k_final(const float2* __restrict__ part2, const float2* __restrict__ z,
             const float* __restrict__ dinv, const float* __restrict__ b2,
             float2* __restrict__ out) {
    int n = blockIdx.x * 256 + threadIdx.x;
    if (n >= N_NODES) return;
    int b = n / SLICE, cl = n - b * SLICE;
    const float2* p = part2 + (size_t)b * NSUB * SLICE + cl;
    float Tx = 0.0f, Ty = 0.0f;
#pragma unroll
    for (int s = 0; s < NSUB; ++s) {
        float2 v = p[(size_t)s * SLICE];
        Tx += v.x; Ty += v.y;
    }
    float di = dinv[n];
    float2 zn = z[n];
    out[n] = make_float2(di * (Tx + zn.x) + b2[0], di * (Ty + zn.y) + b2[1]);
}

// ================= launch =================

extern "C" void kernel_launch(void* const* d_in, const int* in_sizes, int n_in,
                              void* d_out, int out_size, void* d_ws, size_t ws_size,
                              hipStream_t stream) {
    const float* x  = (const float*)d_in[0];
    const int*   ei = (const int*)d_in[1];
    const float* W1 = (const float*)d_in[2];
    const float* b1 = (const float*)d_in[3];
    const float* W2 = (const float*)d_in[4];
    const float* b2 = (const float*)d_in[5];

    const int* row = ei;
    const int* col = ei + N_EDGES;

    char* p = (char*)d_ws;
    unsigned* cnts     = (unsigned*)p;  p += (size_t)NPART * NBUCK * 4;            // 64 KB
    unsigned* bks      = (unsigned*)p;  p += (size_t)NBUCK * NPART * CAPB * 4;     // 8.2 MB
    unsigned* part_deg = (unsigned*)p;  p += (size_t)NBUCK * NSUB * SLICE * 4;     // 2.0 MB
    float*    part1    = (float*)p;     p += (size_t)NBUCK * NSUB * SLICE * 4;     // 2.0 MB
    float2*   part2    = (float2*)p;    p += (size_t)NBUCK * NSUB * SLICE * 8;     // 4.0 MB
    float*    dinv     = (float*)p;     p += N_NODES * 4;
    float*    g        = (float*)p;     p += N_NODES * 4;
    float2*   z        = (float2*)p;

    const int gA = NBUCK * NSUB;            // 320 agg blocks
    const int gN = (N_NODES + 255) / 256;   // 196

    k_part <<<NPART, 256, 0, stream>>>(row, col, cnts, bks);
    k_deg  <<<gA,    256, 0, stream>>>(cnts, bks, part_deg);
    k_g    <<<gN,    256, 0, stream>>>(part_deg, x, dinv, g);
    k_agg1 <<<gA,    256, 0, stream>>>(cnts, bks, g, part1);
    k_mlp  <<<gN,    256, 0, stream>>>(part1, g, dinv, W1, b1, W2, z);
    k_agg2 <<<gA,    256, 0, stream>>>(cnts, bks, z, part2);
    k_final<<<gN,    256, 0, stream>>>(part2, z, dinv, b2, (float2*)d_out);
}

// Round 17
// 112.567 us; speedup vs baseline: 1.4040x; 1.0946x over previous
//
#include <hip/hip_runtime.h>
#include <math.h>

#define N_NODES 50000
#define N_EDGES 800000
#define HIDDEN  64
#define NPART   500                   // partition blocks
#define PCHUNK  1600                  // edges per partition block
#define NBUCK   32
#define SLICE   1568                  // 32*1568 = 50176 >= 50000
#define CAPB    128                   // per-(block,bucket) stage cap: mean 50 + 11 sigma
#define BCAP    26000                 // dense bucket capacity: mean 25088 + 5.8 sigma
#define NSUB    8                     // agg sub-blocks per bucket -> 256 agg blocks

// ws: tails u32[32] | bks u32[32*BCAP] 3.3MB (dense) | part_deg u32[32*NSUB*SLICE] 1.6MB |
//     part1 f32[...] 1.6MB | part2 f32x2[...] 3.2MB | dinv[N] | g[N] | z f2[N]

// ---- K1: write-combined radix partition, DENSE flush via bucket-tail reservation ----
__global__ __launch_bounds__(256)
void k_part(const int* __restrict__ row, const int* __restrict__ col,
            unsigned* __restrict__ tails, unsigned* __restrict__ bks) {
    __shared__ unsigned stage[NBUCK * CAPB];        // 16 KB
    __shared__ unsigned cnt2[NBUCK], gpos[NBUCK];
    const int t   = threadIdx.x;
    const int blk = blockIdx.x;
    const int e0  = blk * PCHUNK;
    if (t < NBUCK) cnt2[t] = 0u;
    __syncthreads();
    const int4* c4 = (const int4*)(col + e0);
    const int4* r4 = (const int4*)(row + e0);
    for (int i = t; i < PCHUNK / 4; i += 256) {     // 400 int4s
        int4 cv = c4[i];
        int4 rv = r4[i];
#pragma unroll
        for (int k = 0; k < 4; ++k) {
            int c = (&cv.x)[k], r = (&rv.x)[k];
            int b = c / SLICE;                      // magic-mul div
            unsigned off = atomicAdd(&cnt2[b], 1u);
            if (off < CAPB)
                stage[(b << 7) + off] = ((unsigned)(c - b * SLICE) << 16) | (unsigned)r;
        }
    }
    __syncthreads();
    if (t < NBUCK) {
        unsigned cc = min(cnt2[t], (unsigned)CAPB);
        cnt2[t] = cc;
        gpos[t] = atomicAdd(&tails[t], cc);         // 16K global atomics total (~1us)
    }
    __syncthreads();
    // dense flush: only valid entries, contiguous per-bucket segments
    for (int i = t; i < NBUCK * CAPB; i += 256) {
        int b = i >> 7; unsigned o = (unsigned)(i & 127);
        if (o < cnt2[b]) {
            unsigned dst = gpos[b] + o;
            if (dst < BCAP) bks[(size_t)b * BCAP + dst] = stage[i];
        }
    }
}

// ---- K2: per-slice degree partials (dense span, predicate-free) ----
__global__ __launch_bounds__(256)
void k_deg(const unsigned* __restrict__ tails, const unsigned* __restrict__ bks,
           unsigned* __restrict__ part_deg) {
    __shared__ unsigned acc[SLICE];                 // 6.3 KB
    const int b = blockIdx.x >> 3;
    const int s = blockIdx.x & (NSUB - 1);
    for (int i = threadIdx.x; i < SLICE; i += 256) acc[i] = 0u;
    __syncthreads();
    unsigned tail = min(tails[b], (unsigned)BCAP);
    unsigned chunk = (tail + NSUB - 1) / NSUB;
    unsigned lo = s * chunk, hi = min(lo + chunk, tail);
    const unsigned* bk = bks + (size_t)b * BCAP;
    for (unsigned i = lo + threadIdx.x; i < hi; i += 256)
        atomicAdd(&acc[bk[i] >> 16], 1u);           // all entries valid
    __syncthreads();
    unsigned* dst = part_deg + (size_t)blockIdx.x * SLICE;
    for (int i = threadIdx.x; i < SLICE; i += 256) dst[i] = acc[i];
}

// ---- K3: reduce NSUB degree partials -> dinv, g = rsqrt(deg+1)*x ----
__global__ __launch_bounds__(256)
void k_g(const unsigned* __restrict__ part_deg, const float* __restrict__ x,
         float* __restrict__ dinv, float* __restrict__ g) {
    int n = blockIdx.x * 256 + threadIdx.x;
    if (n >= N_NODES) return;
    int b = n / SLICE, cl = n - b * SLICE;
    const unsigned* p = part_deg + (size_t)b * NSUB * SLICE + cl;
    unsigned deg = 0;
#pragma unroll
    for (int s = 0; s < NSUB; ++s) deg += p[(size_t)s * SLICE];
    float di = rsqrtf((float)(deg + 1));            // +1 self-loop
    dinv[n] = di;
    g[n] = di * x[n];
}

// ---- K4: layer-1 aggregation (dense, predicate-free) ----
__global__ __launch_bounds__(256)
void k_agg1(const unsigned* __restrict__ tails, const unsigned* __restrict__ bks,
            const float* __restrict__ g, float* __restrict__ part1) {
    __shared__ float acc[SLICE];
    const int b = blockIdx.x >> 3;
    const int s = blockIdx.x & (NSUB - 1);
    for (int i = threadIdx.x; i < SLICE; i += 256) acc[i] = 0.0f;
    __syncthreads();
    unsigned tail = min(tails[b], (unsigned)BCAP);
    unsigned chunk = (tail + NSUB - 1) / NSUB;
    unsigned lo = s * chunk, hi = min(lo + chunk, tail);
    const unsigned* bk = bks + (size_t)b * BCAP;
    for (unsigned i = lo + threadIdx.x; i < hi; i += 256) {
        unsigned v = bk[i];                         // coalesced
        atomicAdd(&acc[v >> 16], g[v & 0xFFFFu]);   // LDS atomic + L2 gather
    }
    __syncthreads();
    float* dst = part1 + (size_t)blockIdx.x * SLICE;
    for (int i = threadIdx.x; i < SLICE; i += 256) dst[i] = acc[i];
}

// ---- K5: reduce NSUB partials + fused MLP -> z ----
__global__ __launch_bounds__(256)
void k_mlp(const float* __restrict__ part1, const float* __restrict__ g,
           const float* __restrict__ dinv,
           const float* __restrict__ W1, const float* __restrict__ b1,
           const float* __restrict__ W2, float2* __restrict__ z) {
    int n = blockIdx.x * 256 + threadIdx.x;
    if (n >= N_NODES) return;
    int b = n / SLICE, cl = n - b * SLICE;
    const float* p = part1 + (size_t)b * NSUB * SLICE + cl;
    float t = 0.0f;
#pragma unroll
    for (int s = 0; s < NSUB; ++s) t += p[(size_t)s * SLICE];
    float di = dinv[n];
    float sv = di * (t + g[n]);
    float y0 = 0.0f, y1 = 0.0f;
#pragma unroll
    for (int k = 0; k < HIDDEN; ++k) {              // wave-uniform -> s_load
        float h = fmaxf(sv * W1[k] + b1[k], 0.0f);
        y0 += h * W2[2 * k];
        y1 += h * W2[2 * k + 1];
    }
    z[n] = make_float2(di * y0, di * y1);
}

// ---- K6: layer-2 aggregation (float2, dense) ----
__global__ __launch_bounds__(256)
void k_agg2(const unsigned* __restrict__ tails, const unsigned* __restrict__ bks,
            const float2* __restrict__ z, float2* __restrict__ part2) {
    __shared__ float ax[SLICE];
    __shared__ float ay[SLICE];
    const int b = blockIdx.x >> 3;
    const int s = blockIdx.x & (NSUB - 1);
    for (int i = threadIdx.x; i < SLICE; i += 256) { ax[i] = 0.0f; ay[i] = 0.0f; }
    __syncthreads();
    unsigned tail = min(tails[b], (unsigned)BCAP);
    unsigned chunk = (tail + NSUB - 1) / NSUB;
    unsigned lo = s * chunk, hi = min(lo + chunk, tail);
    const unsigned* bk = bks + (size_t)b * BCAP;
    for (unsigned i = lo + threadIdx.x; i < hi; i += 256) {
        unsigned v = bk[i];
        float2 zz = z[v & 0xFFFFu];
        unsigned cl = v >> 16;
        atomicAdd(&ax[cl], zz.x);
        atomicAdd(&ay[cl], zz.y);
    }
    __syncthreads();
    float2* dst = part2 + (size_t)blockIdx.x * SLICE;
    for (int i = threadIdx.x; i < SLICE; i += 256) dst[i] = make_float2(ax[i], ay[i]);
}

// ---- K7: reduce NSUB float2 partials + epilogue -> out ----
__global__ __launch_bounds__(256)
void k_final(const float2* __restrict__ part2, const float2* __restrict__ z,
             const float* __restrict__ dinv, const float* __restrict__ b2,
             float2* __restrict__ out) {
    int n = blockIdx.x * 256 + threadIdx.x;
    if (n >= N_NODES) return;
    int b = n / SLICE, cl = n - b * SLICE;
    const float2* p = part2 + (size_t)b * NSUB * SLICE + cl;
    float Tx = 0.0f, Ty = 0.0f;
#pragma unroll
    for (int s = 0; s < NSUB; ++s) {
        float2 v = p[(size_t)s * SLICE];
        Tx += v.x; Ty += v.y;
    }
    float di = dinv[n];
    float2 zn = z[n];
    out[n] = make_float2(di * (Tx + zn.x) + b2[0], di * (Ty + zn.y) + b2[1]);
}

// ================= launch =================

extern "C" void kernel_launch(void* const* d_in, const int* in_sizes, int n_in,
                              void* d_out, int out_size, void* d_ws, size_t ws_size,
                              hipStream_t stream) {
    const float* x  = (const float*)d_in[0];
    const int*   ei = (const int*)d_in[1];
    const float* W1 = (const float*)d_in[2];
    const float* b1 = (const float*)d_in[3];
    const float* W2 = (const float*)d_in[4];
    const float* b2 = (const float*)d_in[5];

    const int* row = ei;
    const int* col = ei + N_EDGES;

    char* p = (char*)d_ws;
    unsigned* tails    = (unsigned*)p;  p += 128;
    unsigned* bks      = (unsigned*)p;  p += (size_t)NBUCK * BCAP * 4;             // 3.3 MB
    unsigned* part_deg = (unsigned*)p;  p += (size_t)NBUCK * NSUB * SLICE * 4;     // 1.6 MB
    float*    part1    = (float*)p;     p += (size_t)NBUCK * NSUB * SLICE * 4;     // 1.6 MB
    float2*   part2    = (float2*)p;    p += (size_t)NBUCK * NSUB * SLICE * 8;     // 3.2 MB
    float*    dinv     = (float*)p;     p += N_NODES * 4;
    float*    g        = (float*)p;     p += N_NODES * 4;
    float2*   z        = (float2*)p;

    const int gA = NBUCK * NSUB;            // 256 agg blocks
    const int gN = (N_NODES + 255) / 256;   // 196

    hipMemsetAsync(tails, 0, NBUCK * sizeof(unsigned), stream);
    k_part <<<NPART, 256, 0, stream>>>(row, col, tails, bks);
    k_deg  <<<gA,    256, 0, stream>>>(tails, bks, part_deg);
    k_g    <<<gN,    256, 0, stream>>>(part_deg, x, dinv, g);
    k_agg1 <<<gA,    256, 0, stream>>>(tails, bks, g, part1);
    k_mlp  <<<gN,    256, 0, stream>>>(part1, g, dinv, W1, b1, W2, z);
    k_agg2 <<<gA,    256, 0, stream>>>(tails, bks, z, part2);
    k_final<<<gN,    256, 0, stream>>>(part2, z, dinv, b2, (float2*)d_out);
}